// Round 1
// baseline (947.373 us; speedup 1.0000x reference)
//
#include <hip/hip_runtime.h>
#include <math.h>

#define NB 512
#define NPQ 128
#define NY 1024
#define NO 256
#define NTOT 1408   // NPQ+NY+NO

// ============================================================================
// Kernel 1: entity encoders -> X[B,N,64], POS[B,N,2]
// 128 rows per block, 256 threads (4 waves x 8 rows x 4 chunks)
// Weight columns cached in 64 VGPRs per lane; h1 broadcast via per-wave LDS.
// ============================================================================
__global__ __launch_bounds__(256) void k_encode(
    const float* __restrict__ pred, const float* __restrict__ prey,
    const float* __restrict__ obst, const float* __restrict__ emb,
    const float* __restrict__ e0w1, const float* __restrict__ e0b1,
    const float* __restrict__ e0w2, const float* __restrict__ e0b2,
    const float* __restrict__ e1w1, const float* __restrict__ e1b1,
    const float* __restrict__ e1w2, const float* __restrict__ e1b2,
    const float* __restrict__ e2w1, const float* __restrict__ e2b1,
    const float* __restrict__ e2w2, const float* __restrict__ e2b2,
    float* __restrict__ X, float* __restrict__ POS)
{
    const int blk = blockIdx.x;
    int type, lrow0, cin, lsh, nmask, nbase;
    const float *st, *w1, *b1, *w2, *b2;
    if (blk < 512)       { type=0; lrow0=blk*128;        st=pred; w1=e0w1; b1=e0b1; w2=e0w2; b2=e0b2; cin=2; lsh=7;  nmask=NPQ-1; nbase=0; }
    else if (blk < 4608) { type=1; lrow0=(blk-512)*128;  st=prey; w1=e1w1; b1=e1b1; w2=e1w2; b2=e1b2; cin=2; lsh=10; nmask=NY-1;  nbase=NPQ; }
    else                 { type=2; lrow0=(blk-4608)*128; st=obst; w1=e2w1; b1=e2b1; w2=e2w2; b2=e2b2; cin=3; lsh=8;  nmask=NO-1;  nbase=NPQ+NY; }

    const int tid = threadIdx.x, lane = tid & 63, wv = tid >> 6;
    __shared__ float wbuf[64*65];      // +1 pad: conflict-free column reads
    __shared__ float hst[4][8][64];    // per-wave h1 stage

    for (int i = tid; i < 4096; i += 256) wbuf[(i>>6)*65 + (i&63)] = w2[i];
    __syncthreads();
    float wreg[64];
    #pragma unroll
    for (int kk = 0; kk < 64; ++kk) wreg[kk] = wbuf[kk*65 + lane];
    const float w1r0 = w1[lane], w1r1 = w1[64+lane];
    const float w1r2 = (cin==3) ? w1[128+lane] : 0.f;
    const float b1r = b1[lane];
    const float b2r = b2[lane] + emb[type*64 + lane];

    for (int chunk = 0; chunk < 4; ++chunk) {
        const int r0 = lrow0 + chunk*32 + wv*8;
        const float* sp = st + (size_t)r0*cin;
        float h1[8];
        #pragma unroll
        for (int rr = 0; rr < 8; ++rr) {
            float a = b1r + sp[rr*cin]*w1r0 + sp[rr*cin+1]*w1r1;
            if (cin==3) a += sp[rr*cin+2]*w1r2;
            h1[rr] = fmaxf(a, 0.f);
        }
        #pragma unroll
        for (int rr = 0; rr < 8; ++rr) hst[wv][rr][lane] = h1[rr];
        float acc[8];
        #pragma unroll
        for (int rr = 0; rr < 8; ++rr) acc[rr] = b2r;
        #pragma unroll
        for (int kk = 0; kk < 64; kk += 4) {
            #pragma unroll
            for (int rr = 0; rr < 8; ++rr) {
                const float4 hb = *(const float4*)&hst[wv][rr][kk];
                acc[rr] = fmaf(hb.x, wreg[kk],   acc[rr]);
                acc[rr] = fmaf(hb.y, wreg[kk+1], acc[rr]);
                acc[rr] = fmaf(hb.z, wreg[kk+2], acc[rr]);
                acc[rr] = fmaf(hb.w, wreg[kk+3], acc[rr]);
            }
        }
        #pragma unroll
        for (int rr = 0; rr < 8; ++rr) {
            const int lr = r0 + rr;
            const int bb = lr >> lsh, n = nbase + (lr & nmask);
            X[((size_t)bb*NTOT + n)*64 + lane] = acc[rr];
        }
        if (lane < 16) {
            const int rr = lane >> 1, c = lane & 1;
            const int lr = r0 + rr;
            const int bb = lr >> lsh, n = nbase + (lr & nmask);
            POS[((size_t)bb*NTOT + n)*2 + c] = st[(size_t)lr*cin + c];
        }
    }
}

// ============================================================================
// Kernel 2: queries. Recompute x_pred, then q=x@wq+bq, qtil=q@wk^T,
// qp=q@wp^T, qc = qp.pos_q + q.(bp+bk).  64 rows/block, 1024 blocks.
// ============================================================================
__global__ __launch_bounds__(256) void k_query(
    const float* __restrict__ pred, const float* __restrict__ emb,
    const float* __restrict__ e0w1, const float* __restrict__ e0b1,
    const float* __restrict__ e0w2, const float* __restrict__ e0b2,
    const float* __restrict__ wq, const float* __restrict__ bq,
    const float* __restrict__ wk, const float* __restrict__ bk,
    const float* __restrict__ wp, const float* __restrict__ bp,
    float* __restrict__ QT, float* __restrict__ QP, float* __restrict__ QC)
{
    const int tid = threadIdx.x, lane = tid & 63, wv = tid >> 6;
    const int p0 = blockIdx.x * 64;
    __shared__ float wbuf[64*65];
    __shared__ float hst[4][8][64];
    __shared__ float xs[64][64];
    __shared__ float qs[64][64];
    float wreg[64];

    // ---- phase 0: x = encoder0(pred rows) ----
    for (int i = tid; i < 4096; i += 256) wbuf[(i>>6)*65 + (i&63)] = e0w2[i];
    __syncthreads();
    #pragma unroll
    for (int kk = 0; kk < 64; ++kk) wreg[kk] = wbuf[kk*65 + lane];
    {
        const float w1r0 = e0w1[lane], w1r1 = e0w1[64+lane];
        const float b1r = e0b1[lane];
        const float b2r = e0b2[lane] + emb[lane];
        for (int chunk = 0; chunk < 2; ++chunk) {
            const int r0 = wv*16 + chunk*8;
            const float* sp = pred + (size_t)(p0 + r0)*2;
            float h1[8];
            #pragma unroll
            for (int rr = 0; rr < 8; ++rr)
                h1[rr] = fmaxf(b1r + sp[rr*2]*w1r0 + sp[rr*2+1]*w1r1, 0.f);
            #pragma unroll
            for (int rr = 0; rr < 8; ++rr) hst[wv][rr][lane] = h1[rr];
            float acc[8];
            #pragma unroll
            for (int rr = 0; rr < 8; ++rr) acc[rr] = b2r;
            #pragma unroll
            for (int kk = 0; kk < 64; kk += 4) {
                #pragma unroll
                for (int rr = 0; rr < 8; ++rr) {
                    const float4 hb = *(const float4*)&hst[wv][rr][kk];
                    acc[rr] = fmaf(hb.x, wreg[kk],   acc[rr]);
                    acc[rr] = fmaf(hb.y, wreg[kk+1], acc[rr]);
                    acc[rr] = fmaf(hb.z, wreg[kk+2], acc[rr]);
                    acc[rr] = fmaf(hb.w, wreg[kk+3], acc[rr]);
                }
            }
            #pragma unroll
            for (int rr = 0; rr < 8; ++rr) xs[r0+rr][lane] = acc[rr];
        }
    }
    __syncthreads();
    // ---- phase 1: q = x@wq + bq ----
    for (int i = tid; i < 4096; i += 256) wbuf[(i>>6)*65 + (i&63)] = wq[i];
    __syncthreads();
    #pragma unroll
    for (int kk = 0; kk < 64; ++kk) wreg[kk] = wbuf[kk*65 + lane];
    {
        const float bqr = bq[lane];
        for (int chunk = 0; chunk < 2; ++chunk) {
            const int r0 = wv*16 + chunk*8;
            float acc[8];
            #pragma unroll
            for (int rr = 0; rr < 8; ++rr) acc[rr] = bqr;
            #pragma unroll
            for (int kk = 0; kk < 64; kk += 4) {
                #pragma unroll
                for (int rr = 0; rr < 8; ++rr) {
                    const float4 xb = *(const float4*)&xs[r0+rr][kk];
                    acc[rr] = fmaf(xb.x, wreg[kk],   acc[rr]);
                    acc[rr] = fmaf(xb.y, wreg[kk+1], acc[rr]);
                    acc[rr] = fmaf(xb.z, wreg[kk+2], acc[rr]);
                    acc[rr] = fmaf(xb.w, wreg[kk+3], acc[rr]);
                }
            }
            #pragma unroll
            for (int rr = 0; rr < 8; ++rr) qs[r0+rr][lane] = acc[rr];
        }
    }
    __syncthreads();
    // ---- phase 2: qtil[j] = sum_kk q[kk]*wk[j][kk]; reductions ----
    for (int i = tid; i < 4096; i += 256) wbuf[(i>>6)*65 + (i&63)] = wk[i];
    __syncthreads();
    #pragma unroll
    for (int kk = 0; kk < 64; ++kk) wreg[kk] = wbuf[lane*65 + kk];  // row `lane` of wk
    {
        const float wp0r = wp[lane], wp1r = wp[64+lane];
        const float bpkr = bp[lane] + bk[lane];
        for (int chunk = 0; chunk < 2; ++chunk) {
            const int r0 = wv*16 + chunk*8;
            float acc[8];
            #pragma unroll
            for (int rr = 0; rr < 8; ++rr) acc[rr] = 0.f;
            #pragma unroll
            for (int kk = 0; kk < 64; kk += 4) {
                #pragma unroll
                for (int rr = 0; rr < 8; ++rr) {
                    const float4 qb = *(const float4*)&qs[r0+rr][kk];
                    acc[rr] = fmaf(qb.x, wreg[kk],   acc[rr]);
                    acc[rr] = fmaf(qb.y, wreg[kk+1], acc[rr]);
                    acc[rr] = fmaf(qb.z, wreg[kk+2], acc[rr]);
                    acc[rr] = fmaf(qb.w, wreg[kk+3], acc[rr]);
                }
            }
            #pragma unroll
            for (int rr = 0; rr < 8; ++rr)
                QT[(size_t)(p0 + r0 + rr)*64 + lane] = acc[rr];
            const float* sp = pred + (size_t)(p0 + r0)*2;
            #pragma unroll
            for (int rr = 0; rr < 8; ++rr) {
                const float qv = qs[r0+rr][lane];
                float v0 = qv * wp0r, v1 = qv * wp1r, v2 = qv * bpkr;
                #pragma unroll
                for (int o = 32; o > 0; o >>= 1) {
                    v0 += __shfl_xor(v0, o);
                    v1 += __shfl_xor(v1, o);
                    v2 += __shfl_xor(v2, o);
                }
                if (lane == 0) {
                    const int p = p0 + r0 + rr;
                    QP[(size_t)p*2]   = v0;
                    QP[(size_t)p*2+1] = v1;
                    QC[p] = v0*sp[rr*2] + v1*sp[rr*2+1] + v2;
                }
            }
        }
    }
}

// ============================================================================
// Kernel 3: flash attention. Block = (batch, 64-query half). 44 key tiles of 32.
// scores = (qtil.x + qc - qp.pos_k) * 0.125 ; online softmax; O = sum p*x / l.
// ============================================================================
__global__ __launch_bounds__(256) void k_attn(
    const float* __restrict__ X, const float* __restrict__ POS,
    const float* __restrict__ QT, const float* __restrict__ QP,
    const float* __restrict__ QC, float* __restrict__ OPRE)
{
    const int tid = threadIdx.x;
    const int b = blockIdx.x >> 1;
    const int q0blk = (blockIdx.x & 1) * 64;
    __shared__ float sQt[64][64];   // qtil transposed: [d][q]
    __shared__ float sXt[64][32];   // X tile transposed: [d][k]
    __shared__ float sXv[32][64];   // X tile row-major:  [k][d]
    __shared__ float sPt[32][64];   // P transposed: [k][q]
    __shared__ float sPos[32][2];
    __shared__ float sM[64], sL[64], sAl[64];
    __shared__ float sQp0[64], sQp1[64], sQc[64];

    const float* qtb = QT + ((size_t)b*NPQ + q0blk)*64;
    for (int i = tid*4; i < 4096; i += 1024) {
        const float4 v = *(const float4*)&qtb[i];
        const int q = i >> 6, d0 = i & 63;
        sQt[d0][q]=v.x; sQt[d0+1][q]=v.y; sQt[d0+2][q]=v.z; sQt[d0+3][q]=v.w;
    }
    if (tid < 64) {
        const size_t qg = (size_t)b*NPQ + q0blk + tid;
        sQp0[tid] = QP[qg*2]; sQp1[tid] = QP[qg*2+1]; sQc[tid] = QC[qg];
        sM[tid] = -1e30f; sL[tid] = 0.f;
    }
    __syncthreads();

    const int qg = tid >> 3, kg = tid & 7, dg = tid & 7;
    const int q0 = qg*2;
    float O[2][8];
    #pragma unroll
    for (int qi=0;qi<2;++qi)
        #pragma unroll
        for (int di=0;di<8;++di) O[qi][di]=0.f;
    float qcr[2], qp0r[2], qp1r[2];
    #pragma unroll
    for (int qi=0;qi<2;++qi){ qcr[qi]=sQc[q0+qi]; qp0r[qi]=sQp0[q0+qi]; qp1r[qi]=sQp1[q0+qi]; }
    const float SC = 0.125f;          // 1/sqrt(64)
    const float L2E = 1.44269504f;

    for (int kt = 0; kt < 44; ++kt) {
        __syncthreads();
        const float* xb = X + ((size_t)b*NTOT + kt*32)*64;
        for (int i = tid*4; i < 2048; i += 1024) {
            const float4 v = *(const float4*)&xb[i];
            const int k = i >> 6, d0 = i & 63;
            sXt[d0][k]=v.x; sXt[d0+1][k]=v.y; sXt[d0+2][k]=v.z; sXt[d0+3][k]=v.w;
            *(float4*)&sXv[k][d0] = v;
        }
        if (tid < 64) {
            const int k = tid >> 1, c = tid & 1;
            sPos[k][c] = POS[((size_t)b*NTOT + kt*32 + k)*2 + c];
        }
        __syncthreads();

        // ---- S phase: 2q x 4k per thread ----
        float acc[2][4];
        #pragma unroll
        for (int qi=0;qi<2;++qi)
            #pragma unroll
            for (int ki=0;ki<4;++ki) acc[qi][ki]=0.f;
        #pragma unroll
        for (int kk = 0; kk < 64; ++kk) {
            const float2 qv = *(const float2*)&sQt[kk][q0];
            const float4 kv = *(const float4*)&sXt[kk][kg*4];
            acc[0][0]=fmaf(qv.x,kv.x,acc[0][0]); acc[0][1]=fmaf(qv.x,kv.y,acc[0][1]);
            acc[0][2]=fmaf(qv.x,kv.z,acc[0][2]); acc[0][3]=fmaf(qv.x,kv.w,acc[0][3]);
            acc[1][0]=fmaf(qv.y,kv.x,acc[1][0]); acc[1][1]=fmaf(qv.y,kv.y,acc[1][1]);
            acc[1][2]=fmaf(qv.y,kv.z,acc[1][2]); acc[1][3]=fmaf(qv.y,kv.w,acc[1][3]);
        }
        float sc[2][4], p[2][4], mx[2];
        #pragma unroll
        for (int qi=0;qi<2;++qi) {
            #pragma unroll
            for (int ki=0;ki<4;++ki) {
                const int k = kg*4+ki;
                sc[qi][ki] = (acc[qi][ki] + qcr[qi]
                              - qp0r[qi]*sPos[k][0] - qp1r[qi]*sPos[k][1]) * SC;
            }
            mx[qi] = fmaxf(fmaxf(sc[qi][0],sc[qi][1]),fmaxf(sc[qi][2],sc[qi][3]));
        }
        #pragma unroll
        for (int o=1;o<8;o<<=1) {
            mx[0] = fmaxf(mx[0], __shfl_xor(mx[0], o));
            mx[1] = fmaxf(mx[1], __shfl_xor(mx[1], o));
        }
        float lsum[2], mold[2], mnew[2];
        #pragma unroll
        for (int qi=0;qi<2;++qi) {
            mold[qi] = sM[q0+qi];
            mnew[qi] = fmaxf(mold[qi], mx[qi]);
            lsum[qi] = 0.f;
            #pragma unroll
            for (int ki=0;ki<4;++ki) {
                p[qi][ki] = exp2f((sc[qi][ki]-mnew[qi])*L2E);
                lsum[qi] += p[qi][ki];
            }
        }
        #pragma unroll
        for (int o=1;o<8;o<<=1) {
            lsum[0] += __shfl_xor(lsum[0], o);
            lsum[1] += __shfl_xor(lsum[1], o);
        }
        if (kg == 0) {
            #pragma unroll
            for (int qi=0;qi<2;++qi) {
                const float al = exp2f((mold[qi]-mnew[qi])*L2E);
                sAl[q0+qi] = al;
                sM[q0+qi] = mnew[qi];
                sL[q0+qi] = sL[q0+qi]*al + lsum[qi];
            }
        }
        #pragma unroll
        for (int ki=0;ki<4;++ki)
            *(float2*)&sPt[kg*4+ki][q0] = make_float2(p[0][ki], p[1][ki]);
        __syncthreads();

        // ---- PV phase: 2q x 8d per thread ----
        float al0 = sAl[q0], al1 = sAl[q0+1];
        #pragma unroll
        for (int di=0;di<8;++di){ O[0][di]*=al0; O[1][di]*=al1; }
        #pragma unroll
        for (int k=0;k<32;++k) {
            const float2 pv = *(const float2*)&sPt[k][q0];
            const float4 v0 = *(const float4*)&sXv[k][dg*8];
            const float4 v1 = *(const float4*)&sXv[k][dg*8+4];
            O[0][0]=fmaf(pv.x,v0.x,O[0][0]); O[0][1]=fmaf(pv.x,v0.y,O[0][1]);
            O[0][2]=fmaf(pv.x,v0.z,O[0][2]); O[0][3]=fmaf(pv.x,v0.w,O[0][3]);
            O[0][4]=fmaf(pv.x,v1.x,O[0][4]); O[0][5]=fmaf(pv.x,v1.y,O[0][5]);
            O[0][6]=fmaf(pv.x,v1.z,O[0][6]); O[0][7]=fmaf(pv.x,v1.w,O[0][7]);
            O[1][0]=fmaf(pv.y,v0.x,O[1][0]); O[1][1]=fmaf(pv.y,v0.y,O[1][1]);
            O[1][2]=fmaf(pv.y,v0.z,O[1][2]); O[1][3]=fmaf(pv.y,v0.w,O[1][3]);
            O[1][4]=fmaf(pv.y,v1.x,O[1][4]); O[1][5]=fmaf(pv.y,v1.y,O[1][5]);
            O[1][6]=fmaf(pv.y,v1.z,O[1][6]); O[1][7]=fmaf(pv.y,v1.w,O[1][7]);
        }
    }
    const float rl0 = 1.f/sL[q0], rl1 = 1.f/sL[q0+1];
    {
        float* dst0 = OPRE + ((size_t)b*NPQ + q0blk + q0)*64 + dg*8;
        float* dst1 = OPRE + ((size_t)b*NPQ + q0blk + q0 + 1)*64 + dg*8;
        *(float4*)dst0     = make_float4(O[0][0]*rl0,O[0][1]*rl0,O[0][2]*rl0,O[0][3]*rl0);
        *(float4*)(dst0+4) = make_float4(O[0][4]*rl0,O[0][5]*rl0,O[0][6]*rl0,O[0][7]*rl0);
        *(float4*)dst1     = make_float4(O[1][0]*rl1,O[1][1]*rl1,O[1][2]*rl1,O[1][3]*rl1);
        *(float4*)(dst1+4) = make_float4(O[1][4]*rl1,O[1][5]*rl1,O[1][6]*rl1,O[1][7]*rl1);
    }
}

// ============================================================================
// Kernel 4: output head: OPRE @wv+bv @wo+bo, relu@n_w1, relu@n_w2, tanh(.n_w3+b3)
// 64 rows/block, 1024 blocks. Ping-pong LDS stages.
// ============================================================================
__global__ __launch_bounds__(256) void k_head(
    const float* __restrict__ OPRE,
    const float* __restrict__ wv, const float* __restrict__ bv,
    const float* __restrict__ wo, const float* __restrict__ bo,
    const float* __restrict__ nw1, const float* __restrict__ nb1,
    const float* __restrict__ nw2, const float* __restrict__ nb2,
    const float* __restrict__ nw3, const float* __restrict__ nb3,
    float* __restrict__ OUT)
{
    const int tid = threadIdx.x, lane = tid & 63, wv4 = tid >> 6;
    const int p0 = blockIdx.x * 64;
    __shared__ float wbuf[64*65];
    __shared__ float sa[64][64];
    __shared__ float sb[64][64];

    for (int i = tid; i < 4096; i += 256) sa[i>>6][i&63] = OPRE[(size_t)p0*64 + i];

    for (int l = 0; l < 4; ++l) {
        __syncthreads();
        const float *W, *Bb;
        if (l==0)      { W=wv;  Bb=bv;  }
        else if (l==1) { W=wo;  Bb=bo;  }
        else if (l==2) { W=nw1; Bb=nb1; }
        else           { W=nw2; Bb=nb2; }
        for (int i = tid; i < 4096; i += 256) wbuf[(i>>6)*65 + (i&63)] = W[i];
        __syncthreads();
        float wreg[64];
        #pragma unroll
        for (int kk = 0; kk < 64; ++kk) wreg[kk] = wbuf[kk*65 + lane];
        const float br = Bb[lane];
        const bool doRelu = (l >= 2);
        float (*src)[64] = (l & 1) ? sb : sa;
        float (*dst)[64] = (l & 1) ? sa : sb;
        for (int chunk = 0; chunk < 2; ++chunk) {
            const int r0 = wv4*16 + chunk*8;
            float acc[8];
            #pragma unroll
            for (int rr=0;rr<8;++rr) acc[rr] = br;
            #pragma unroll
            for (int kk = 0; kk < 64; kk += 4) {
                #pragma unroll
                for (int rr = 0; rr < 8; ++rr) {
                    const float4 xb = *(const float4*)&src[r0+rr][kk];
                    acc[rr] = fmaf(xb.x, wreg[kk],   acc[rr]);
                    acc[rr] = fmaf(xb.y, wreg[kk+1], acc[rr]);
                    acc[rr] = fmaf(xb.z, wreg[kk+2], acc[rr]);
                    acc[rr] = fmaf(xb.w, wreg[kk+3], acc[rr]);
                }
            }
            #pragma unroll
            for (int rr=0;rr<8;++rr)
                dst[r0+rr][lane] = doRelu ? fmaxf(acc[rr],0.f) : acc[rr];
        }
    }
    __syncthreads();
    const float w3r = nw3[lane];
    const float b3 = nb3[0];
    for (int chunk = 0; chunk < 2; ++chunk) {
        const int r0 = wv4*16 + chunk*8;
        #pragma unroll
        for (int rr=0;rr<8;++rr) {
            float v = sa[r0+rr][lane] * w3r;
            #pragma unroll
            for (int o=32;o>0;o>>=1) v += __shfl_xor(v, o);
            if (lane == 0) OUT[p0 + r0 + rr] = tanhf(v + b3);
        }
    }
}

// ============================================================================
extern "C" void kernel_launch(void* const* d_in, const int* in_sizes, int n_in,
                              void* d_out, int out_size, void* d_ws, size_t ws_size,
                              hipStream_t stream)
{
    const float* pred = (const float*)d_in[0];
    const float* prey = (const float*)d_in[1];
    const float* obst = (const float*)d_in[2];
    // d_in[3] = prey_is_alive: unused (reference mask is identically False)
    const float* emb  = (const float*)d_in[4];
    const float* e0w1 = (const float*)d_in[5];
    const float* e0b1 = (const float*)d_in[6];
    const float* e0w2 = (const float*)d_in[7];
    const float* e0b2 = (const float*)d_in[8];
    const float* e1w1 = (const float*)d_in[9];
    const float* e1b1 = (const float*)d_in[10];
    const float* e1w2 = (const float*)d_in[11];
    const float* e1b2 = (const float*)d_in[12];
    const float* e2w1 = (const float*)d_in[13];
    const float* e2b1 = (const float*)d_in[14];
    const float* e2w2 = (const float*)d_in[15];
    const float* e2b2 = (const float*)d_in[16];
    const float* wq  = (const float*)d_in[17];
    const float* bq  = (const float*)d_in[18];
    const float* wk  = (const float*)d_in[19];
    const float* bk  = (const float*)d_in[20];
    const float* wvv = (const float*)d_in[21];
    const float* bv  = (const float*)d_in[22];
    const float* wp  = (const float*)d_in[23];
    const float* bp  = (const float*)d_in[24];
    const float* wo  = (const float*)d_in[25];
    const float* bo  = (const float*)d_in[26];
    const float* nw1 = (const float*)d_in[27];
    const float* nb1 = (const float*)d_in[28];
    const float* nw2 = (const float*)d_in[29];
    const float* nb2 = (const float*)d_in[30];
    const float* nw3 = (const float*)d_in[31];
    const float* nb3 = (const float*)d_in[32];

    float* ws  = (float*)d_ws;
    float* X   = ws;                 // 512*1408*64 = 46,137,344 f32
    float* POS = X   + 46137344;     // 512*1408*2  =  1,441,792
    float* QT  = POS + 1441792;      // 512*128*64  =  4,194,304
    float* QP  = QT  + 4194304;      // 512*128*2   =    131,072
    float* QC  = QP  + 131072;       // 512*128     =     65,536
    float* OPRE= QC  + 65536;        // 512*128*64  =  4,194,304
    // total ws: 56,164,352 floats = 224.7 MB

    k_encode<<<5632, 256, 0, stream>>>(pred, prey, obst, emb,
        e0w1,e0b1,e0w2,e0b2, e1w1,e1b1,e1w2,e1b2, e2w1,e2b1,e2w2,e2b2, X, POS);
    k_query<<<1024, 256, 0, stream>>>(pred, emb, e0w1,e0b1,e0w2,e0b2,
        wq,bq, wk,bk, wp,bp, QT,QP,QC);
    k_attn<<<1024, 256, 0, stream>>>(X, POS, QT, QP, QC, OPRE);
    k_head<<<1024, 256, 0, stream>>>(OPRE, wvv,bv, wo,bo, nw1,nb1, nw2,nb2, nw3,nb3,
        (float*)d_out);
}

// Round 3
// 491.683 us; speedup vs baseline: 1.9268x; 1.9268x over previous
//
#include <hip/hip_runtime.h>
#include <math.h>

#define NB 512
#define NPQ 128
#define NY 1024
#define NO 256
#define NTOT 1408   // NPQ+NY+NO

typedef __attribute__((ext_vector_type(8))) short bf16x8;
typedef __attribute__((ext_vector_type(4))) float f32x4;

__device__ __forceinline__ unsigned short f2bf(float f) {
    unsigned int u = __float_as_uint(f);
    u += 0x7fffu + ((u >> 16) & 1u);   // RTNE
    return (unsigned short)(u >> 16);
}

// ============================================================================
// Kernel 1: entity encoders -> X[B,N,64] (bf16), POS[B,N,2] (f32)
// ============================================================================
__global__ __launch_bounds__(256) void k_encode(
    const float* __restrict__ pred, const float* __restrict__ prey,
    const float* __restrict__ obst, const float* __restrict__ emb,
    const float* __restrict__ e0w1, const float* __restrict__ e0b1,
    const float* __restrict__ e0w2, const float* __restrict__ e0b2,
    const float* __restrict__ e1w1, const float* __restrict__ e1b1,
    const float* __restrict__ e1w2, const float* __restrict__ e1b2,
    const float* __restrict__ e2w1, const float* __restrict__ e2b1,
    const float* __restrict__ e2w2, const float* __restrict__ e2b2,
    unsigned short* __restrict__ X, float* __restrict__ POS)
{
    const int blk = blockIdx.x;
    int type, lrow0, cin, lsh, nmask, nbase;
    const float *st, *w1, *b1, *w2, *b2;
    if (blk < 512)       { type=0; lrow0=blk*128;        st=pred; w1=e0w1; b1=e0b1; w2=e0w2; b2=e0b2; cin=2; lsh=7;  nmask=NPQ-1; nbase=0; }
    else if (blk < 4608) { type=1; lrow0=(blk-512)*128;  st=prey; w1=e1w1; b1=e1b1; w2=e1w2; b2=e1b2; cin=2; lsh=10; nmask=NY-1;  nbase=NPQ; }
    else                 { type=2; lrow0=(blk-4608)*128; st=obst; w1=e2w1; b1=e2b1; w2=e2w2; b2=e2b2; cin=3; lsh=8;  nmask=NO-1;  nbase=NPQ+NY; }

    const int tid = threadIdx.x, lane = tid & 63, wv = tid >> 6;
    __shared__ float wbuf[64*65];
    __shared__ float hst[4][8][64];

    for (int i = tid; i < 4096; i += 256) wbuf[(i>>6)*65 + (i&63)] = w2[i];
    __syncthreads();
    float wreg[64];
    #pragma unroll
    for (int kk = 0; kk < 64; ++kk) wreg[kk] = wbuf[kk*65 + lane];
    const float w1r0 = w1[lane], w1r1 = w1[64+lane];
    const float w1r2 = (cin==3) ? w1[128+lane] : 0.f;
    const float b1r = b1[lane];
    const float b2r = b2[lane] + emb[type*64 + lane];

    for (int chunk = 0; chunk < 4; ++chunk) {
        const int r0 = lrow0 + chunk*32 + wv*8;
        const float* sp = st + (size_t)r0*cin;
        float h1[8];
        #pragma unroll
        for (int rr = 0; rr < 8; ++rr) {
            float a = b1r + sp[rr*cin]*w1r0 + sp[rr*cin+1]*w1r1;
            if (cin==3) a += sp[rr*cin+2]*w1r2;
            h1[rr] = fmaxf(a, 0.f);
        }
        #pragma unroll
        for (int rr = 0; rr < 8; ++rr) hst[wv][rr][lane] = h1[rr];
        float acc[8];
        #pragma unroll
        for (int rr = 0; rr < 8; ++rr) acc[rr] = b2r;
        #pragma unroll
        for (int kk = 0; kk < 64; kk += 4) {
            #pragma unroll
            for (int rr = 0; rr < 8; ++rr) {
                const float4 hb = *(const float4*)&hst[wv][rr][kk];
                acc[rr] = fmaf(hb.x, wreg[kk],   acc[rr]);
                acc[rr] = fmaf(hb.y, wreg[kk+1], acc[rr]);
                acc[rr] = fmaf(hb.z, wreg[kk+2], acc[rr]);
                acc[rr] = fmaf(hb.w, wreg[kk+3], acc[rr]);
            }
        }
        #pragma unroll
        for (int rr = 0; rr < 8; ++rr) {
            const int lr = r0 + rr;
            const int bb = lr >> lsh, n = nbase + (lr & nmask);
            X[((size_t)bb*NTOT + n)*64 + lane] = f2bf(acc[rr]);
        }
        if (lane < 16) {
            const int rr = lane >> 1, c = lane & 1;
            const int lr = r0 + rr;
            const int bb = lr >> lsh, n = nbase + (lr & nmask);
            POS[((size_t)bb*NTOT + n)*2 + c] = st[(size_t)lr*cin + c];
        }
    }
}

// ============================================================================
// Kernel 2: queries. q=x@wq+bq, qtil=q@wk^T (f32), qp=q@wp^T, qc folded const.
// ============================================================================
__global__ __launch_bounds__(256) void k_query(
    const float* __restrict__ pred, const float* __restrict__ emb,
    const float* __restrict__ e0w1, const float* __restrict__ e0b1,
    const float* __restrict__ e0w2, const float* __restrict__ e0b2,
    const float* __restrict__ wq, const float* __restrict__ bq,
    const float* __restrict__ wk, const float* __restrict__ bk,
    const float* __restrict__ wp, const float* __restrict__ bp,
    float* __restrict__ QT, float* __restrict__ QP, float* __restrict__ QC)
{
    const int tid = threadIdx.x, lane = tid & 63, wv = tid >> 6;
    const int p0 = blockIdx.x * 64;
    __shared__ float wbuf[64*65];
    __shared__ float hst[4][8][64];
    __shared__ float xs[64][64];
    __shared__ float qs[64][64];
    float wreg[64];

    for (int i = tid; i < 4096; i += 256) wbuf[(i>>6)*65 + (i&63)] = e0w2[i];
    __syncthreads();
    #pragma unroll
    for (int kk = 0; kk < 64; ++kk) wreg[kk] = wbuf[kk*65 + lane];
    {
        const float w1r0 = e0w1[lane], w1r1 = e0w1[64+lane];
        const float b1r = e0b1[lane];
        const float b2r = e0b2[lane] + emb[lane];
        for (int chunk = 0; chunk < 2; ++chunk) {
            const int r0 = wv*16 + chunk*8;
            const float* sp = pred + (size_t)(p0 + r0)*2;
            float h1[8];
            #pragma unroll
            for (int rr = 0; rr < 8; ++rr)
                h1[rr] = fmaxf(b1r + sp[rr*2]*w1r0 + sp[rr*2+1]*w1r1, 0.f);
            #pragma unroll
            for (int rr = 0; rr < 8; ++rr) hst[wv][rr][lane] = h1[rr];
            float acc[8];
            #pragma unroll
            for (int rr = 0; rr < 8; ++rr) acc[rr] = b2r;
            #pragma unroll
            for (int kk = 0; kk < 64; kk += 4) {
                #pragma unroll
                for (int rr = 0; rr < 8; ++rr) {
                    const float4 hb = *(const float4*)&hst[wv][rr][kk];
                    acc[rr] = fmaf(hb.x, wreg[kk],   acc[rr]);
                    acc[rr] = fmaf(hb.y, wreg[kk+1], acc[rr]);
                    acc[rr] = fmaf(hb.z, wreg[kk+2], acc[rr]);
                    acc[rr] = fmaf(hb.w, wreg[kk+3], acc[rr]);
                }
            }
            #pragma unroll
            for (int rr = 0; rr < 8; ++rr) xs[r0+rr][lane] = acc[rr];
        }
    }
    __syncthreads();
    for (int i = tid; i < 4096; i += 256) wbuf[(i>>6)*65 + (i&63)] = wq[i];
    __syncthreads();
    #pragma unroll
    for (int kk = 0; kk < 64; ++kk) wreg[kk] = wbuf[kk*65 + lane];
    {
        const float bqr = bq[lane];
        for (int chunk = 0; chunk < 2; ++chunk) {
            const int r0 = wv*16 + chunk*8;
            float acc[8];
            #pragma unroll
            for (int rr = 0; rr < 8; ++rr) acc[rr] = bqr;
            #pragma unroll
            for (int kk = 0; kk < 64; kk += 4) {
                #pragma unroll
                for (int rr = 0; rr < 8; ++rr) {
                    const float4 xb = *(const float4*)&xs[r0+rr][kk];
                    acc[rr] = fmaf(xb.x, wreg[kk],   acc[rr]);
                    acc[rr] = fmaf(xb.y, wreg[kk+1], acc[rr]);
                    acc[rr] = fmaf(xb.z, wreg[kk+2], acc[rr]);
                    acc[rr] = fmaf(xb.w, wreg[kk+3], acc[rr]);
                }
            }
            #pragma unroll
            for (int rr = 0; rr < 8; ++rr) qs[r0+rr][lane] = acc[rr];
        }
    }
    __syncthreads();
    for (int i = tid; i < 4096; i += 256) wbuf[(i>>6)*65 + (i&63)] = wk[i];
    __syncthreads();
    #pragma unroll
    for (int kk = 0; kk < 64; ++kk) wreg[kk] = wbuf[lane*65 + kk];  // row `lane` of wk
    {
        const float wp0r = wp[lane], wp1r = wp[64+lane];
        const float bpkr = bp[lane] + bk[lane];
        for (int chunk = 0; chunk < 2; ++chunk) {
            const int r0 = wv*16 + chunk*8;
            float acc[8];
            #pragma unroll
            for (int rr = 0; rr < 8; ++rr) acc[rr] = 0.f;
            #pragma unroll
            for (int kk = 0; kk < 64; kk += 4) {
                #pragma unroll
                for (int rr = 0; rr < 8; ++rr) {
                    const float4 qb = *(const float4*)&qs[r0+rr][kk];
                    acc[rr] = fmaf(qb.x, wreg[kk],   acc[rr]);
                    acc[rr] = fmaf(qb.y, wreg[kk+1], acc[rr]);
                    acc[rr] = fmaf(qb.z, wreg[kk+2], acc[rr]);
                    acc[rr] = fmaf(qb.w, wreg[kk+3], acc[rr]);
                }
            }
            #pragma unroll
            for (int rr = 0; rr < 8; ++rr)
                QT[(size_t)(p0 + r0 + rr)*64 + lane] = acc[rr];
            const float* sp = pred + (size_t)(p0 + r0)*2;
            #pragma unroll
            for (int rr = 0; rr < 8; ++rr) {
                const float qv = qs[r0+rr][lane];
                float v0 = qv * wp0r, v1 = qv * wp1r, v2 = qv * bpkr;
                #pragma unroll
                for (int o = 32; o > 0; o >>= 1) {
                    v0 += __shfl_xor(v0, o);
                    v1 += __shfl_xor(v1, o);
                    v2 += __shfl_xor(v2, o);
                }
                if (lane == 0) {
                    const int p = p0 + r0 + rr;
                    QP[(size_t)p*2]   = v0;
                    QP[(size_t)p*2+1] = v1;
                    QC[p] = v0*sp[rr*2] + v1*sp[rr*2+1] + v2;
                }
            }
        }
    }
}

// ============================================================================
// Kernel 3: MFMA flash attention. Block = (batch, q-half of 64). 4 waves x 16q.
// 22 key tiles of 64. mfma_f32_16x16x32_bf16, verified layouts:
//   A[m=lane&15][k=quad*8+j] (m120); C/D col=lane&15, row=quad*4+reg (m89/91);
//   B mirrors A from row-major X (m97 gemm_bt pattern).
// R3 fix: mid-tile __syncthreads() between sP writes (S-phase, C/D layout)
// and sP reads (PV A-frags) — forces the LDS round-trip ordering instead of
// relying on same-wave DS in-order + compiler alias analysis (R2's failure:
// PV consumed garbage bf16 from sP -> O exploded -> tanh saturated to +-1).
// Next tile's global->reg prefetch issues before the S-phase; its LDS writes
// land after the mid barrier (other buffer, race-free).
// ============================================================================
__global__ __launch_bounds__(256) void k_attn(
    const unsigned short* __restrict__ X, const float* __restrict__ POS,
    const float* __restrict__ QT, const float* __restrict__ QP,
    const float* __restrict__ QC, float* __restrict__ OPRE)
{
    const int tid = threadIdx.x;
    const int b = blockIdx.x >> 1;
    const int qh = blockIdx.x & 1;
    const int w = tid >> 6, lane = tid & 63, lq = lane & 15, quad = lane >> 4;
    const int qbase = qh*64 + w*16;

    __shared__ __align__(16) short sXc[2][64][68];   // [buf][d][key] bf16 (X^T)
    __shared__ __align__(16) short sP[4][16*68];     // per-wave [q][key] bf16
    __shared__ float sPos[2][2][64];                 // [buf][coord][key]

    // ---- one-time preloads ----
    const float* qrow = QT + ((size_t)b*NPQ + qbase + lq)*64;
    bf16x8 aq0, aq1;
    #pragma unroll
    for (int j = 0; j < 8; ++j) aq0[j] = (short)f2bf(qrow[quad*8 + j]);
    #pragma unroll
    for (int j = 0; j < 8; ++j) aq1[j] = (short)f2bf(qrow[32 + quad*8 + j]);

    float qcr[4], qp0r[4], qp1r[4], lacc[4];
    f32x4 O[4];
    #pragma unroll
    for (int i = 0; i < 4; ++i) {
        const size_t g = (size_t)b*NPQ + qbase + quad*4 + i;
        qcr[i]  = QC[g];
        qp0r[i] = -QP[2*g];
        qp1r[i] = -QP[2*g+1];
        lacc[i] = 0.f;
        O[i] = (f32x4){0.f, 0.f, 0.f, 0.f};
    }
    const float E = 0.180336884f;   // (1/sqrt(64)) * log2(e)

    const int skey = tid & 63, sd0 = (tid >> 6) * 16;

    // ---- stage tile 0 into buffer 0 ----
    {
        const unsigned short* gx = X + ((size_t)b*NTOT + skey)*64 + sd0;
        uint4 t0 = *(const uint4*)(gx);
        uint4 t1 = *(const uint4*)(gx + 8);
        unsigned short tmp[16];
        *(uint4*)tmp = t0; *(uint4*)(tmp+8) = t1;
        #pragma unroll
        for (int j = 0; j < 16; ++j) sXc[0][sd0+j][skey] = (short)tmp[j];
        if (tid < 128)
            sPos[0][tid&1][tid>>1] = POS[((size_t)b*NTOT + (tid>>1))*2 + (tid&1)];
    }
    __syncthreads();

    for (int kt = 0; kt < 22; ++kt) {
        const int bb = kt & 1;
        const bool pf = (kt + 1 < 22);

        // ---- prefetch next tile: global -> registers (no LDS writes yet) ----
        uint4 t0, t1; float posreg = 0.f;
        if (pf) {
            const unsigned short* gx = X + ((size_t)b*NTOT + (kt+1)*64 + skey)*64 + sd0;
            t0 = *(const uint4*)(gx);
            t1 = *(const uint4*)(gx + 8);
            if (tid < 128)
                posreg = POS[((size_t)b*NTOT + (kt+1)*64 + (tid>>1))*2 + (tid&1)];
        }

        // ---- S phase: B-frags from global (row-major X), 8 MFMAs ----
        union U16 { bf16x8 v; uint4 u; };
        U16 bx[4][2];
        #pragma unroll
        for (int nt = 0; nt < 4; ++nt) {
            const unsigned short* xrow = X + ((size_t)b*NTOT + kt*64 + nt*16 + lq)*64;
            bx[nt][0].u = *(const uint4*)(xrow + quad*8);
            bx[nt][1].u = *(const uint4*)(xrow + 32 + quad*8);
        }
        #pragma unroll
        for (int nt = 0; nt < 4; ++nt) {
            f32x4 acc = {0.f, 0.f, 0.f, 0.f};
            acc = __builtin_amdgcn_mfma_f32_16x16x32_bf16(aq0, bx[nt][0].v, acc, 0, 0, 0);
            acc = __builtin_amdgcn_mfma_f32_16x16x32_bf16(aq1, bx[nt][1].v, acc, 0, 0, 0);
            const float pos0 = sPos[bb][0][nt*16 + lq];
            const float pos1 = sPos[bb][1][nt*16 + lq];
            #pragma unroll
            for (int i = 0; i < 4; ++i) {
                float s = acc[i] + qcr[i];
                s = fmaf(qp0r[i], pos0, s);   // qp0r pre-negated
                s = fmaf(qp1r[i], pos1, s);
                const float p = exp2f(s * E);
                lacc[i] += p;
                sP[w][(quad*4 + i)*68 + nt*16 + lq] = (short)f2bf(p);
            }
        }

        __syncthreads();   // << R3 fix: order sP writes before sP reads

        // ---- write prefetched tile into the other buffer ----
        if (pf) {
            unsigned short tmp[16];
            *(uint4*)tmp = t0; *(uint4*)(tmp+8) = t1;
            #pragma unroll
            for (int j = 0; j < 16; ++j) sXc[bb^1][sd0+j][skey] = (short)tmp[j];
            if (tid < 128) sPos[bb^1][tid&1][tid>>1] = posreg;
        }

        // ---- PV phase: A = P (LDS), B = X^T (LDS), 8 MFMAs ----
        #pragma unroll
        for (int kc = 0; kc < 2; ++kc) {
            union U8 { bf16x8 v; unsigned long long u[2]; };
            U8 pa;
            const short* pp = &sP[w][lq*68 + kc*32 + quad*8];
            pa.u[0] = *(const unsigned long long*)pp;
            pa.u[1] = *(const unsigned long long*)(pp + 4);
            #pragma unroll
            for (int nt = 0; nt < 4; ++nt) {
                U8 bv;
                const short* xp = &sXc[bb][nt*16 + lq][kc*32 + quad*8];
                bv.u[0] = *(const unsigned long long*)xp;
                bv.u[1] = *(const unsigned long long*)(xp + 4);
                O[nt] = __builtin_amdgcn_mfma_f32_16x16x32_bf16(pa.v, bv.v, O[nt], 0, 0, 0);
            }
        }
        __syncthreads();
    }

    // ---- epilogue: reduce l across the 16-lane column groups, write O/l ----
    #pragma unroll
    for (int i = 0; i < 4; ++i) {
        #pragma unroll
        for (int off = 1; off < 16; off <<= 1) lacc[i] += __shfl_xor(lacc[i], off);
    }
    #pragma unroll
    for (int i = 0; i < 4; ++i) {
        const float rl = 1.f / lacc[i];
        float* orow = OPRE + ((size_t)b*NPQ + qbase + quad*4 + i)*64;
        #pragma unroll
        for (int nt = 0; nt < 4; ++nt) orow[nt*16 + lq] = O[nt][i] * rl;
    }
}

// ============================================================================
// Kernel 4: output head
// ============================================================================
__global__ __launch_bounds__(256) void k_head(
    const float* __restrict__ OPRE,
    const float* __restrict__ wv, const float* __restrict__ bv,
    const float* __restrict__ wo, const float* __restrict__ bo,
    const float* __restrict__ nw1, const float* __restrict__ nb1,
    const float* __restrict__ nw2, const float* __restrict__ nb2,
    const float* __restrict__ nw3, const float* __restrict__ nb3,
    float* __restrict__ OUT)
{
    const int tid = threadIdx.x, lane = tid & 63, wv4 = tid >> 6;
    const int p0 = blockIdx.x * 64;
    __shared__ float wbuf[64*65];
    __shared__ float sa[64][64];
    __shared__ float sb[64][64];

    for (int i = tid; i < 4096; i += 256) sa[i>>6][i&63] = OPRE[(size_t)p0*64 + i];

    for (int l = 0; l < 4; ++l) {
        __syncthreads();
        const float *W, *Bb;
        if (l==0)      { W=wv;  Bb=bv;  }
        else if (l==1) { W=wo;  Bb=bo;  }
        else if (l==2) { W=nw1; Bb=nb1; }
        else           { W=nw2; Bb=nb2; }
        for (int i = tid; i < 4096; i += 256) wbuf[(i>>6)*65 + (i&63)] = W[i];
        __syncthreads();
        float wreg[64];
        #pragma unroll
        for (int kk = 0; kk < 64; ++kk) wreg[kk] = wbuf[kk*65 + lane];
        const float br = Bb[lane];
        const bool doRelu = (l >= 2);
        float (*src)[64] = (l & 1) ? sb : sa;
        float (*dst)[64] = (l & 1) ? sa : sb;
        for (int chunk = 0; chunk < 2; ++chunk) {
            const int r0 = wv4*16 + chunk*8;
            float acc[8];
            #pragma unroll
            for (int rr=0;rr<8;++rr) acc[rr] = br;
            #pragma unroll
            for (int kk = 0; kk < 64; kk += 4) {
                #pragma unroll
                for (int rr = 0; rr < 8; ++rr) {
                    const float4 xb = *(const float4*)&src[r0+rr][kk];
                    acc[rr] = fmaf(xb.x, wreg[kk],   acc[rr]);
                    acc[rr] = fmaf(xb.y, wreg[kk+1], acc[rr]);
                    acc[rr] = fmaf(xb.z, wreg[kk+2], acc[rr]);
                    acc[rr] = fmaf(xb.w, wreg[kk+3], acc[rr]);
                }
            }
            #pragma unroll
            for (int rr=0;rr<8;++rr)
                dst[r0+rr][lane] = doRelu ? fmaxf(acc[rr],0.f) : acc[rr];
        }
    }
    __syncthreads();
    const float w3r = nw3[lane];
    const float b3 = nb3[0];
    for (int chunk = 0; chunk < 2; ++chunk) {
        const int r0 = wv4*16 + chunk*8;
        #pragma unroll
        for (int rr=0;rr<8;++rr) {
            float v = sa[r0+rr][lane] * w3r;
            #pragma unroll
            for (int o=32;o>0;o>>=1) v += __shfl_xor(v, o);
            if (lane == 0) OUT[p0 + r0 + rr] = tanhf(v + b3);
        }
    }
}

// ============================================================================
extern "C" void kernel_launch(void* const* d_in, const int* in_sizes, int n_in,
                              void* d_out, int out_size, void* d_ws, size_t ws_size,
                              hipStream_t stream)
{
    const float* pred = (const float*)d_in[0];
    const float* prey = (const float*)d_in[1];
    const float* obst = (const float*)d_in[2];
    const float* emb  = (const float*)d_in[4];
    const float* e0w1 = (const float*)d_in[5];
    const float* e0b1 = (const float*)d_in[6];
    const float* e0w2 = (const float*)d_in[7];
    const float* e0b2 = (const float*)d_in[8];
    const float* e1w1 = (const float*)d_in[9];
    const float* e1b1 = (const float*)d_in[10];
    const float* e1w2 = (const float*)d_in[11];
    const float* e1b2 = (const float*)d_in[12];
    const float* e2w1 = (const float*)d_in[13];
    const float* e2b1 = (const float*)d_in[14];
    const float* e2w2 = (const float*)d_in[15];
    const float* e2b2 = (const float*)d_in[16];
    const float* wq  = (const float*)d_in[17];
    const float* bq  = (const float*)d_in[18];
    const float* wk  = (const float*)d_in[19];
    const float* bk  = (const float*)d_in[20];
    const float* wvv = (const float*)d_in[21];
    const float* bv  = (const float*)d_in[22];
    const float* wp  = (const float*)d_in[23];
    const float* bp  = (const float*)d_in[24];
    const float* wo  = (const float*)d_in[25];
    const float* bo  = (const float*)d_in[26];
    const float* nw1 = (const float*)d_in[27];
    const float* nb1 = (const float*)d_in[28];
    const float* nw2 = (const float*)d_in[29];
    const float* nb2 = (const float*)d_in[30];
    const float* nw3 = (const float*)d_in[31];
    const float* nb3 = (const float*)d_in[32];

    char* ws = (char*)d_ws;
    unsigned short* X = (unsigned short*)ws;          // 512*1408*64 bf16 = 92,274,688 B
    float* POS = (float*)(ws + 92274688);             // 512*1408*2 f32
    float* QT  = POS + 1441792;                       // 512*128*64 f32
    float* QP  = QT  + 4194304;                       // 512*128*2
    float* QC  = QP  + 131072;                        // 512*128
    float* OPRE= QC  + 65536;                         // 512*128*64
    // total ~126 MB

    k_encode<<<5632, 256, 0, stream>>>(pred, prey, obst, emb,
        e0w1,e0b1,e0w2,e0b2, e1w1,e1b1,e1w2,e1b2, e2w1,e2b1,e2w2,e2b2, X, POS);
    k_query<<<1024, 256, 0, stream>>>(pred, emb, e0w1,e0b1,e0w2,e0b2,
        wq,bq, wk,bk, wp,bp, QT,QP,QC);
    k_attn<<<1024, 256, 0, stream>>>(X, POS, QT, QP, QC, OPRE);
    k_head<<<1024, 256, 0, stream>>>(OPRE, wvv,bv, wo,bo, nw1,nb1, nw2,nb2, nw3,nb3,
        (float*)d_out);
}

// Round 4
// 444.082 us; speedup vs baseline: 2.1333x; 1.1072x over previous
//
#include <hip/hip_runtime.h>
#include <math.h>

#define NB 512
#define NPQ 128
#define NY 1024
#define NO 256
#define NTOT 1408   // NPQ+NY+NO

typedef __attribute__((ext_vector_type(8))) short bf16x8;
typedef __attribute__((ext_vector_type(4))) float f32x4;

__device__ __forceinline__ unsigned short f2bf(float f) {
    unsigned int u = __float_as_uint(f);
    u += 0x7fffu + ((u >> 16) & 1u);   // RTNE
    return (unsigned short)(u >> 16);
}

// ============================================================================
// Kernel 1: entity encoders -> X[B,N,64] (bf16), POS[B,N,2] (f32)
// R4: layer-2 (h1 @ w2) on MFMA. Layouts (HW-verified, same as k_attn):
//   A[m][k]: m=lane&15, k=quad*8+j  -> A = w2 columns: A[m=d][k] = w2[k][d]
//   B[n][k]: n=lane&15, k=quad*8+j  -> B = h1 rows (row-major LDS, stride 72)
//   D[m][n]: col=lane&15 = n = entity row; row m = d = quad*4+reg
// => lane holds 4 consecutive d per m-tile -> packed 8B stores, no epilogue LDS.
// Layer-1 (K=2/3) stays VALU: lane computes h1[r][k=lane], 4 param regs,
// wave-uniform state rows (scalar loads). h1 staged via per-wave dbuf LDS with
// an explicit __syncthreads() between writes and B-frag reads (R2 lesson).
// ============================================================================
__global__ __launch_bounds__(256) void k_encode(
    const float* __restrict__ pred, const float* __restrict__ prey,
    const float* __restrict__ obst, const float* __restrict__ emb,
    const float* __restrict__ e0w1, const float* __restrict__ e0b1,
    const float* __restrict__ e0w2, const float* __restrict__ e0b2,
    const float* __restrict__ e1w1, const float* __restrict__ e1b1,
    const float* __restrict__ e1w2, const float* __restrict__ e1b2,
    const float* __restrict__ e2w1, const float* __restrict__ e2b1,
    const float* __restrict__ e2w2, const float* __restrict__ e2b2,
    unsigned short* __restrict__ X, float* __restrict__ POS)
{
    const int blk = blockIdx.x;
    int type, lrow0, cin, lsh, nmask, nbase;
    const float *st, *w1, *b1, *w2, *b2;
    if (blk < 512)       { type=0; lrow0=blk*128;        st=pred; w1=e0w1; b1=e0b1; w2=e0w2; b2=e0b2; cin=2; lsh=7;  nmask=NPQ-1; nbase=0; }
    else if (blk < 4608) { type=1; lrow0=(blk-512)*128;  st=prey; w1=e1w1; b1=e1b1; w2=e1w2; b2=e1b2; cin=2; lsh=10; nmask=NY-1;  nbase=NPQ; }
    else                 { type=2; lrow0=(blk-4608)*128; st=obst; w1=e2w1; b1=e2b1; w2=e2w2; b2=e2b2; cin=3; lsh=8;  nmask=NO-1;  nbase=NPQ+NY; }

    const int tid = threadIdx.x, lane = tid & 63, w = tid >> 6;
    const int lq = lane & 15, quad = lane >> 4;

    __shared__ __align__(16) short sH[4][2][16][72];   // [wave][dbuf][row][k] bf16

    // ---- w2 A-frags: wfrag[mt][kh][j] = w2[(kh*32+quad*8+j)][mt*16+lq] ----
    bf16x8 wfrag[4][2];
    #pragma unroll
    for (int mt = 0; mt < 4; ++mt)
        #pragma unroll
        for (int kh = 0; kh < 2; ++kh)
            #pragma unroll
            for (int j = 0; j < 8; ++j)
                wfrag[mt][kh][j] = (short)f2bf(w2[(kh*32 + quad*8 + j)*64 + mt*16 + lq]);

    // ---- bias + emb for my d-set: d = mt*16 + quad*4 + i ----
    float be[4][4];
    #pragma unroll
    for (int mt = 0; mt < 4; ++mt) {
        const float4 bb4 = *(const float4*)&b2[mt*16 + quad*4];
        const float4 ee4 = *(const float4*)&emb[type*64 + mt*16 + quad*4];
        be[mt][0] = bb4.x + ee4.x; be[mt][1] = bb4.y + ee4.y;
        be[mt][2] = bb4.z + ee4.z; be[mt][3] = bb4.w + ee4.w;
    }

    // ---- layer-1 params for k = lane ----
    const float w1r0 = w1[lane], w1r1 = w1[64+lane];
    const float w1r2 = (cin==3) ? w1[128+lane] : 0.f;
    const float b1r = b1[lane];

    // ---- POS: one store per thread covers 128 rows x 2 coords ----
    {
        const int r = tid >> 1, c = tid & 1;
        const int lr = lrow0 + r;
        const int pb = lr >> lsh, n = nbase + (lr & nmask);
        POS[((size_t)pb*NTOT + n)*2 + c] = st[(size_t)lr*cin + c];
    }

    for (int rt = 0; rt < 2; ++rt) {
        const int r0 = lrow0 + w*32 + rt*16;
        // layer-1: h1[r][lane] for the wave's 16 rows (state rows wave-uniform)
        const float* sp = st + (size_t)r0*cin;
        #pragma unroll
        for (int r = 0; r < 16; ++r) {
            float a = b1r + sp[r*cin]*w1r0 + sp[r*cin+1]*w1r1;
            if (cin==3) a += sp[r*cin+2]*w1r2;
            sH[w][rt][r][lane] = (short)f2bf(fmaxf(a, 0.f));
        }
        __syncthreads();   // order h1 writes before B-frag reads (R2 lesson)

        // B-frags: h1 rows
        union U8 { bf16x8 v; unsigned long long u[2]; };
        bf16x8 hb[2];
        #pragma unroll
        for (int kh = 0; kh < 2; ++kh)
            hb[kh] = *(const bf16x8*)&sH[w][rt][lq][kh*32 + quad*8];

        f32x4 acc[4];
        #pragma unroll
        for (int mt = 0; mt < 4; ++mt) acc[mt] = (f32x4){0.f,0.f,0.f,0.f};
        #pragma unroll
        for (int mt = 0; mt < 4; ++mt) {
            acc[mt] = __builtin_amdgcn_mfma_f32_16x16x32_bf16(wfrag[mt][0], hb[0], acc[mt], 0, 0, 0);
            acc[mt] = __builtin_amdgcn_mfma_f32_16x16x32_bf16(wfrag[mt][1], hb[1], acc[mt], 0, 0, 0);
        }

        // store: entity row = r0 + lq; lane holds d = mt*16 + quad*4 + i
        const int lr = r0 + lq;
        const int bb = lr >> lsh, n = nbase + (lr & nmask);
        unsigned short* xbase = X + ((size_t)bb*NTOT + n)*64;
        #pragma unroll
        for (int mt = 0; mt < 4; ++mt) {
            const unsigned int u0 = (unsigned int)f2bf(acc[mt][0] + be[mt][0])
                                  | ((unsigned int)f2bf(acc[mt][1] + be[mt][1]) << 16);
            const unsigned int u1 = (unsigned int)f2bf(acc[mt][2] + be[mt][2])
                                  | ((unsigned int)f2bf(acc[mt][3] + be[mt][3]) << 16);
            *(uint2*)(xbase + mt*16 + quad*4) = make_uint2(u0, u1);
        }
    }
}

// ============================================================================
// Kernel 2: queries. q=x@wq+bq, qtil=q@wk^T (f32), qp=q@wp^T, qc folded const.
// ============================================================================
__global__ __launch_bounds__(256) void k_query(
    const float* __restrict__ pred, const float* __restrict__ emb,
    const float* __restrict__ e0w1, const float* __restrict__ e0b1,
    const float* __restrict__ e0w2, const float* __restrict__ e0b2,
    const float* __restrict__ wq, const float* __restrict__ bq,
    const float* __restrict__ wk, const float* __restrict__ bk,
    const float* __restrict__ wp, const float* __restrict__ bp,
    float* __restrict__ QT, float* __restrict__ QP, float* __restrict__ QC)
{
    const int tid = threadIdx.x, lane = tid & 63, wv = tid >> 6;
    const int p0 = blockIdx.x * 64;
    __shared__ float wbuf[64*65];
    __shared__ float hst[4][8][64];
    __shared__ float xs[64][64];
    __shared__ float qs[64][64];
    float wreg[64];

    for (int i = tid; i < 4096; i += 256) wbuf[(i>>6)*65 + (i&63)] = e0w2[i];
    __syncthreads();
    #pragma unroll
    for (int kk = 0; kk < 64; ++kk) wreg[kk] = wbuf[kk*65 + lane];
    {
        const float w1r0 = e0w1[lane], w1r1 = e0w1[64+lane];
        const float b1r = e0b1[lane];
        const float b2r = e0b2[lane] + emb[lane];
        for (int chunk = 0; chunk < 2; ++chunk) {
            const int r0 = wv*16 + chunk*8;
            const float* sp = pred + (size_t)(p0 + r0)*2;
            float h1[8];
            #pragma unroll
            for (int rr = 0; rr < 8; ++rr)
                h1[rr] = fmaxf(b1r + sp[rr*2]*w1r0 + sp[rr*2+1]*w1r1, 0.f);
            #pragma unroll
            for (int rr = 0; rr < 8; ++rr) hst[wv][rr][lane] = h1[rr];
            float acc[8];
            #pragma unroll
            for (int rr = 0; rr < 8; ++rr) acc[rr] = b2r;
            #pragma unroll
            for (int kk = 0; kk < 64; kk += 4) {
                #pragma unroll
                for (int rr = 0; rr < 8; ++rr) {
                    const float4 hb = *(const float4*)&hst[wv][rr][kk];
                    acc[rr] = fmaf(hb.x, wreg[kk],   acc[rr]);
                    acc[rr] = fmaf(hb.y, wreg[kk+1], acc[rr]);
                    acc[rr] = fmaf(hb.z, wreg[kk+2], acc[rr]);
                    acc[rr] = fmaf(hb.w, wreg[kk+3], acc[rr]);
                }
            }
            #pragma unroll
            for (int rr = 0; rr < 8; ++rr) xs[r0+rr][lane] = acc[rr];
        }
    }
    __syncthreads();
    for (int i = tid; i < 4096; i += 256) wbuf[(i>>6)*65 + (i&63)] = wq[i];
    __syncthreads();
    #pragma unroll
    for (int kk = 0; kk < 64; ++kk) wreg[kk] = wbuf[kk*65 + lane];
    {
        const float bqr = bq[lane];
        for (int chunk = 0; chunk < 2; ++chunk) {
            const int r0 = wv*16 + chunk*8;
            float acc[8];
            #pragma unroll
            for (int rr = 0; rr < 8; ++rr) acc[rr] = bqr;
            #pragma unroll
            for (int kk = 0; kk < 64; kk += 4) {
                #pragma unroll
                for (int rr = 0; rr < 8; ++rr) {
                    const float4 xb = *(const float4*)&xs[r0+rr][kk];
                    acc[rr] = fmaf(xb.x, wreg[kk],   acc[rr]);
                    acc[rr] = fmaf(xb.y, wreg[kk+1], acc[rr]);
                    acc[rr] = fmaf(xb.z, wreg[kk+2], acc[rr]);
                    acc[rr] = fmaf(xb.w, wreg[kk+3], acc[rr]);
                }
            }
            #pragma unroll
            for (int rr = 0; rr < 8; ++rr) qs[r0+rr][lane] = acc[rr];
        }
    }
    __syncthreads();
    for (int i = tid; i < 4096; i += 256) wbuf[(i>>6)*65 + (i&63)] = wk[i];
    __syncthreads();
    #pragma unroll
    for (int kk = 0; kk < 64; ++kk) wreg[kk] = wbuf[lane*65 + kk];  // row `lane` of wk
    {
        const float wp0r = wp[lane], wp1r = wp[64+lane];
        const float bpkr = bp[lane] + bk[lane];
        for (int chunk = 0; chunk < 2; ++chunk) {
            const int r0 = wv*16 + chunk*8;
            float acc[8];
            #pragma unroll
            for (int rr = 0; rr < 8; ++rr) acc[rr] = 0.f;
            #pragma unroll
            for (int kk = 0; kk < 64; kk += 4) {
                #pragma unroll
                for (int rr = 0; rr < 8; ++rr) {
                    const float4 qb = *(const float4*)&qs[r0+rr][kk];
                    acc[rr] = fmaf(qb.x, wreg[kk],   acc[rr]);
                    acc[rr] = fmaf(qb.y, wreg[kk+1], acc[rr]);
                    acc[rr] = fmaf(qb.z, wreg[kk+2], acc[rr]);
                    acc[rr] = fmaf(qb.w, wreg[kk+3], acc[rr]);
                }
            }
            #pragma unroll
            for (int rr = 0; rr < 8; ++rr)
                QT[(size_t)(p0 + r0 + rr)*64 + lane] = acc[rr];
            const float* sp = pred + (size_t)(p0 + r0)*2;
            #pragma unroll
            for (int rr = 0; rr < 8; ++rr) {
                const float qv = qs[r0+rr][lane];
                float v0 = qv * wp0r, v1 = qv * wp1r, v2 = qv * bpkr;
                #pragma unroll
                for (int o = 32; o > 0; o >>= 1) {
                    v0 += __shfl_xor(v0, o);
                    v1 += __shfl_xor(v1, o);
                    v2 += __shfl_xor(v2, o);
                }
                if (lane == 0) {
                    const int p = p0 + r0 + rr;
                    QP[(size_t)p*2]   = v0;
                    QP[(size_t)p*2+1] = v1;
                    QC[p] = v0*sp[rr*2] + v1*sp[rr*2+1] + v2;
                }
            }
        }
    }
}

// ============================================================================
// Kernel 3: MFMA flash attention (unchanged from R3 — verified).
// ============================================================================
__global__ __launch_bounds__(256) void k_attn(
    const unsigned short* __restrict__ X, const float* __restrict__ POS,
    const float* __restrict__ QT, const float* __restrict__ QP,
    const float* __restrict__ QC, float* __restrict__ OPRE)
{
    const int tid = threadIdx.x;
    const int b = blockIdx.x >> 1;
    const int qh = blockIdx.x & 1;
    const int w = tid >> 6, lane = tid & 63, lq = lane & 15, quad = lane >> 4;
    const int qbase = qh*64 + w*16;

    __shared__ __align__(16) short sXc[2][64][68];   // [buf][d][key] bf16 (X^T)
    __shared__ __align__(16) short sP[4][16*68];     // per-wave [q][key] bf16
    __shared__ float sPos[2][2][64];                 // [buf][coord][key]

    const float* qrow = QT + ((size_t)b*NPQ + qbase + lq)*64;
    bf16x8 aq0, aq1;
    #pragma unroll
    for (int j = 0; j < 8; ++j) aq0[j] = (short)f2bf(qrow[quad*8 + j]);
    #pragma unroll
    for (int j = 0; j < 8; ++j) aq1[j] = (short)f2bf(qrow[32 + quad*8 + j]);

    float qcr[4], qp0r[4], qp1r[4], lacc[4];
    f32x4 O[4];
    #pragma unroll
    for (int i = 0; i < 4; ++i) {
        const size_t g = (size_t)b*NPQ + qbase + quad*4 + i;
        qcr[i]  = QC[g];
        qp0r[i] = -QP[2*g];
        qp1r[i] = -QP[2*g+1];
        lacc[i] = 0.f;
        O[i] = (f32x4){0.f, 0.f, 0.f, 0.f};
    }
    const float E = 0.180336884f;   // (1/sqrt(64)) * log2(e)

    const int skey = tid & 63, sd0 = (tid >> 6) * 16;

    {
        const unsigned short* gx = X + ((size_t)b*NTOT + skey)*64 + sd0;
        uint4 t0 = *(const uint4*)(gx);
        uint4 t1 = *(const uint4*)(gx + 8);
        unsigned short tmp[16];
        *(uint4*)tmp = t0; *(uint4*)(tmp+8) = t1;
        #pragma unroll
        for (int j = 0; j < 16; ++j) sXc[0][sd0+j][skey] = (short)tmp[j];
        if (tid < 128)
            sPos[0][tid&1][tid>>1] = POS[((size_t)b*NTOT + (tid>>1))*2 + (tid&1)];
    }
    __syncthreads();

    for (int kt = 0; kt < 22; ++kt) {
        const int bb = kt & 1;
        const bool pf = (kt + 1 < 22);

        uint4 t0, t1; float posreg = 0.f;
        if (pf) {
            const unsigned short* gx = X + ((size_t)b*NTOT + (kt+1)*64 + skey)*64 + sd0;
            t0 = *(const uint4*)(gx);
            t1 = *(const uint4*)(gx + 8);
            if (tid < 128)
                posreg = POS[((size_t)b*NTOT + (kt+1)*64 + (tid>>1))*2 + (tid&1)];
        }

        union U16 { bf16x8 v; uint4 u; };
        U16 bx[4][2];
        #pragma unroll
        for (int nt = 0; nt < 4; ++nt) {
            const unsigned short* xrow = X + ((size_t)b*NTOT + kt*64 + nt*16 + lq)*64;
            bx[nt][0].u = *(const uint4*)(xrow + quad*8);
            bx[nt][1].u = *(const uint4*)(xrow + 32 + quad*8);
        }
        #pragma unroll
        for (int nt = 0; nt < 4; ++nt) {
            f32x4 acc = {0.f, 0.f, 0.f, 0.f};
            acc = __builtin_amdgcn_mfma_f32_16x16x32_bf16(aq0, bx[nt][0].v, acc, 0, 0, 0);
            acc = __builtin_amdgcn_mfma_f32_16x16x32_bf16(aq1, bx[nt][1].v, acc, 0, 0, 0);
            const float pos0 = sPos[bb][0][nt*16 + lq];
            const float pos1 = sPos[bb][1][nt*16 + lq];
            #pragma unroll
            for (int i = 0; i < 4; ++i) {
                float s = acc[i] + qcr[i];
                s = fmaf(qp0r[i], pos0, s);
                s = fmaf(qp1r[i], pos1, s);
                const float p = exp2f(s * E);
                lacc[i] += p;
                sP[w][(quad*4 + i)*68 + nt*16 + lq] = (short)f2bf(p);
            }
        }

        __syncthreads();   // order sP writes before sP reads

        if (pf) {
            unsigned short tmp[16];
            *(uint4*)tmp = t0; *(uint4*)(tmp+8) = t1;
            #pragma unroll
            for (int j = 0; j < 16; ++j) sXc[bb^1][sd0+j][skey] = (short)tmp[j];
            if (tid < 128) sPos[bb^1][tid&1][tid>>1] = posreg;
        }

        #pragma unroll
        for (int kc = 0; kc < 2; ++kc) {
            union U8 { bf16x8 v; unsigned long long u[2]; };
            U8 pa;
            const short* pp = &sP[w][lq*68 + kc*32 + quad*8];
            pa.u[0] = *(const unsigned long long*)pp;
            pa.u[1] = *(const unsigned long long*)(pp + 4);
            #pragma unroll
            for (int nt = 0; nt < 4; ++nt) {
                U8 bv;
                const short* xp = &sXc[bb][nt*16 + lq][kc*32 + quad*8];
                bv.u[0] = *(const unsigned long long*)xp;
                bv.u[1] = *(const unsigned long long*)(xp + 4);
                O[nt] = __builtin_amdgcn_mfma_f32_16x16x32_bf16(pa.v, bv.v, O[nt], 0, 0, 0);
            }
        }
        __syncthreads();
    }

    #pragma unroll
    for (int i = 0; i < 4; ++i) {
        #pragma unroll
        for (int off = 1; off < 16; off <<= 1) lacc[i] += __shfl_xor(lacc[i], off);
    }
    #pragma unroll
    for (int i = 0; i < 4; ++i) {
        const float rl = 1.f / lacc[i];
        float* orow = OPRE + ((size_t)b*NPQ + qbase + quad*4 + i)*64;
        #pragma unroll
        for (int nt = 0; nt < 4; ++nt) orow[nt*16 + lq] = O[nt][i] * rl;
    }
}

// ============================================================================
// Kernel 4: output head
// ============================================================================
__global__ __launch_bounds__(256) void k_head(
    const float* __restrict__ OPRE,
    const float* __restrict__ wv, const float* __restrict__ bv,
    const float* __restrict__ wo, const float* __restrict__ bo,
    const float* __restrict__ nw1, const float* __restrict__ nb1,
    const float* __restrict__ nw2, const float* __restrict__ nb2,
    const float* __restrict__ nw3, const float* __restrict__ nb3,
    float* __restrict__ OUT)
{
    const int tid = threadIdx.x, lane = tid & 63, wv4 = tid >> 6;
    const int p0 = blockIdx.x * 64;
    __shared__ float wbuf[64*65];
    __shared__ float sa[64][64];
    __shared__ float sb[64][64];

    for (int i = tid; i < 4096; i += 256) sa[i>>6][i&63] = OPRE[(size_t)p0*64 + i];

    for (int l = 0; l < 4; ++l) {
        __syncthreads();
        const float *W, *Bb;
        if (l==0)      { W=wv;  Bb=bv;  }
        else if (l==1) { W=wo;  Bb=bo;  }
        else if (l==2) { W=nw1; Bb=nb1; }
        else           { W=nw2; Bb=nb2; }
        for (int i = tid; i < 4096; i += 256) wbuf[(i>>6)*65 + (i&63)] = W[i];
        __syncthreads();
        float wreg[64];
        #pragma unroll
        for (int kk = 0; kk < 64; ++kk) wreg[kk] = wbuf[kk*65 + lane];
        const float br = Bb[lane];
        const bool doRelu = (l >= 2);
        float (*src)[64] = (l & 1) ? sb : sa;
        float (*dst)[64] = (l & 1) ? sa : sb;
        for (int chunk = 0; chunk < 2; ++chunk) {
            const int r0 = wv4*16 + chunk*8;
            float acc[8];
            #pragma unroll
            for (int rr=0;rr<8;++rr) acc[rr] = br;
            #pragma unroll
            for (int kk = 0; kk < 64; kk += 4) {
                #pragma unroll
                for (int rr = 0; rr < 8; ++rr) {
                    const float4 xb = *(const float4*)&src[r0+rr][kk];
                    acc[rr] = fmaf(xb.x, wreg[kk],   acc[rr]);
                    acc[rr] = fmaf(xb.y, wreg[kk+1], acc[rr]);
                    acc[rr] = fmaf(xb.z, wreg[kk+2], acc[rr]);
                    acc[rr] = fmaf(xb.w, wreg[kk+3], acc[rr]);
                }
            }
            #pragma unroll
            for (int rr=0;rr<8;++rr)
                dst[r0+rr][lane] = doRelu ? fmaxf(acc[rr],0.f) : acc[rr];
        }
    }
    __syncthreads();
    const float w3r = nw3[lane];
    const float b3 = nb3[0];
    for (int chunk = 0; chunk < 2; ++chunk) {
        const int r0 = wv4*16 + chunk*8;
        #pragma unroll
        for (int rr=0;rr<8;++rr) {
            float v = sa[r0+rr][lane] * w3r;
            #pragma unroll
            for (int o=32;o>0;o>>=1) v += __shfl_xor(v, o);
            if (lane == 0) OUT[p0 + r0 + rr] = tanhf(v + b3);
        }
    }
}

// ============================================================================
extern "C" void kernel_launch(void* const* d_in, const int* in_sizes, int n_in,
                              void* d_out, int out_size, void* d_ws, size_t ws_size,
                              hipStream_t stream)
{
    const float* pred = (const float*)d_in[0];
    const float* prey = (const float*)d_in[1];
    const float* obst = (const float*)d_in[2];
    const float* emb  = (const float*)d_in[4];
    const float* e0w1 = (const float*)d_in[5];
    const float* e0b1 = (const float*)d_in[6];
    const float* e0w2 = (const float*)d_in[7];
    const float* e0b2 = (const float*)d_in[8];
    const float* e1w1 = (const float*)d_in[9];
    const float* e1b1 = (const float*)d_in[10];
    const float* e1w2 = (const float*)d_in[11];
    const float* e1b2 = (const float*)d_in[12];
    const float* e2w1 = (const float*)d_in[13];
    const float* e2b1 = (const float*)d_in[14];
    const float* e2w2 = (const float*)d_in[15];
    const float* e2b2 = (const float*)d_in[16];
    const float* wq  = (const float*)d_in[17];
    const float* bq  = (const float*)d_in[18];
    const float* wk  = (const float*)d_in[19];
    const float* bk  = (const float*)d_in[20];
    const float* wvv = (const float*)d_in[21];
    const float* bv  = (const float*)d_in[22];
    const float* wp  = (const float*)d_in[23];
    const float* bp  = (const float*)d_in[24];
    const float* wo  = (const float*)d_in[25];
    const float* bo  = (const float*)d_in[26];
    const float* nw1 = (const float*)d_in[27];
    const float* nb1 = (const float*)d_in[28];
    const float* nw2 = (const float*)d_in[29];
    const float* nb2 = (const float*)d_in[30];
    const float* nw3 = (const float*)d_in[31];
    const float* nb3 = (const float*)d_in[32];

    char* ws = (char*)d_ws;
    unsigned short* X = (unsigned short*)ws;          // 512*1408*64 bf16 = 92,274,688 B
    float* POS = (float*)(ws + 92274688);             // 512*1408*2 f32
    float* QT  = POS + 1441792;                       // 512*128*64 f32
    float* QP  = QT  + 4194304;                       // 512*128*2
    float* QC  = QP  + 131072;                        // 512*128
    float* OPRE= QC  + 65536;                         // 512*128*64

    k_encode<<<5632, 256, 0, stream>>>(pred, prey, obst, emb,
        e0w1,e0b1,e0w2,e0b2, e1w1,e1b1,e1w2,e1b2, e2w1,e2b1,e2w2,e2b2, X, POS);
    k_query<<<1024, 256, 0, stream>>>(pred, emb, e0w1,e0b1,e0w2,e0b2,
        wq,bq, wk,bk, wp,bp, QT,QP,QC);
    k_attn<<<1024, 256, 0, stream>>>(X, POS, QT, QP, QC, OPRE);
    k_head<<<1024, 256, 0, stream>>>(OPRE, wvv,bv, wo,bo, nw1,nb1, nw2,nb2, nw3,nb3,
        (float*)d_out);
}